// Round 9
// baseline (347.067 us; speedup 1.0000x reference)
//
#include <hip/hip_runtime.h>
#include <hip/hip_bf16.h>
#include <cstdint>
#include <cstddef>

#define NTOK 8192
#define DH   2048
#define DF   1376
#define NE   8
#define CAP  1280

typedef __bf16 bf16x8 __attribute__((ext_vector_type(8)));
typedef float  f32x4  __attribute__((ext_vector_type(4)));

#define BARRIER() asm volatile("s_barrier" ::: "memory")
#define WAITV(n)  asm volatile("s_waitcnt vmcnt(" #n ")" ::: "memory")
#define LGKM0()   asm volatile("s_waitcnt lgkmcnt(0)" ::: "memory")
#define SCHED0()  __builtin_amdgcn_sched_barrier(0)
#define SETPRIO(n) __builtin_amdgcn_s_setprio(n)

__device__ __forceinline__ uint32_t pk2(float a, float b) {
  float2 f; f.x = a; f.y = b;
  union { __hip_bfloat162 h; uint32_t u; } cv;
  cv.h = __float22bfloat162_rn(f);
  return cv.u;
}
__device__ __forceinline__ ushort bf16bits(float a) {
  return (ushort)(pk2(a, 0.f) & 0xFFFFu);
}
__device__ __forceinline__ void gload16(const ushort* g, ushort* l) {
  __builtin_amdgcn_global_load_lds(
      (const __attribute__((address_space(1))) uint32_t*)(const void*)g,
      (__attribute__((address_space(3))) uint32_t*)(void*)l,
      16, 0, 0);
}

// ---- rowpair-128B layout for BK=32 tiles (proven: 0 bank conflicts) ----
__device__ __forceinline__ void rp_src(int o, int& row, int& ko) {
  int p = o >> 7;
  int g = ((o >> 4) & 7) ^ (p & 7);
  row = p * 2 + (g >> 2);
  ko  = (g & 3) * 8;
}
__device__ __forceinline__ int rp_off(int row, int l4) {
  return ((row >> 1) << 7) + (((((row & 1) << 2) + l4) ^ ((row >> 1) & 7)) << 4);
}

// ---------------- routing ----------------
__global__ void routing_kernel(const int* __restrict__ idx, int* __restrict__ tok_slot,
                               int* __restrict__ tok_keep) {
  __shared__ int cnt[256][NE];
  const int t = threadIdx.x;
  for (int s = t; s < NE * CAP; s += 256) tok_slot[s] = -1;
  unsigned long long cA = 0ull, cB = 0ull;
  const int per = NTOK / 256, base = t * per;
  for (int i = 0; i < per; ++i) {
    int e = idx[base + i];
    unsigned long long inc = 1ull << ((e & 3) * 16);
    if (e < 4) cA += inc; else cB += inc;
  }
#pragma unroll
  for (int e = 0; e < 4; ++e) cnt[t][e]     = (int)((cA >> (e * 16)) & 0xFFFF);
#pragma unroll
  for (int e = 0; e < 4; ++e) cnt[t][4 + e] = (int)((cB >> (e * 16)) & 0xFFFF);
  __syncthreads();
  if (t < NE) {
    int run = 0;
    for (int i = 0; i < 256; ++i) { int c = cnt[i][t]; cnt[i][t] = run; run += c; }
  }
  __syncthreads();
  cA = 0ull; cB = 0ull;
#pragma unroll
  for (int e = 0; e < 4; ++e) cA |= (unsigned long long)(cnt[t][e] & 0xFFFF) << (e * 16);
#pragma unroll
  for (int e = 0; e < 4; ++e) cB |= (unsigned long long)(cnt[t][4 + e] & 0xFFFF) << (e * 16);
  for (int i = 0; i < per; ++i) {
    int token = base + i;
    int e = idx[token];
    int sh = (e & 3) * 16;
    int r = (int)(((e < 4 ? cA : cB) >> sh) & 0xFFFF);
    unsigned long long inc = 1ull << sh;
    if (e < 4) cA += inc; else cB += inc;
    bool keep = (r < CAP);
    tok_keep[token] = keep ? 1 : 0;
    if (keep) tok_slot[e * CAP + r] = token;
  }
}

// ---------------- x f32 -> bf16, fused zero of dropped y rows ----------------
__global__ void xconv_zero(const float* __restrict__ x, const int* __restrict__ keep,
                           ushort* __restrict__ xb, float* __restrict__ y) {
  const int row = blockIdx.x;
  const int c = threadIdx.x * 8;
  const size_t off = (size_t)row * DH + c;
  float4 a = *(const float4*)(x + off);
  float4 b = *(const float4*)(x + off + 4);
  uint4 p = { pk2(a.x, a.y), pk2(a.z, a.w), pk2(b.x, b.y), pk2(b.z, b.w) };
  *(uint4*)(xb + off) = p;
  if (!keep[row]) {
    float4 z = {0.f, 0.f, 0.f, 0.f};
    *(float4*)(y + off) = z;
    *(float4*)(y + off + 4) = z;
  }
}

// ---------------- all 3 weights: [E][K][N] f32 -> [E][N][K] bf16 ----------------
__global__ __launch_bounds__(256) void transpose_all(
    const float* __restrict__ wg, const float* __restrict__ wu, const float* __restrict__ wd,
    ushort* __restrict__ wgt, ushort* __restrict__ wut, ushort* __restrict__ wdt) {
  const int z = blockIdx.z;
  const float* in; ushort* out; int K, N, eidx;
  if (z < 8)       { in = wg; out = wgt; K = DH; N = DF; eidx = z; }
  else if (z < 16) { in = wu; out = wut; K = DH; N = DF; eidx = z - 8; }
  else             { in = wd; out = wdt; K = DF; N = DH; eidx = z - 16; }
  const int n0 = blockIdx.x * 64, k0 = blockIdx.y * 64;
  if (n0 >= N || k0 >= K) return;
  __shared__ ushort T[64][72];
  const int tid = threadIdx.x;
  const size_t eoff_in  = (size_t)eidx * K * N;
  const size_t eoff_out = (size_t)eidx * N * K;
  const int kr = tid >> 4;
  const int nc = (tid & 15) * 4;
#pragma unroll
  for (int it = 0; it < 4; ++it) {
    int k = k0 + kr + it * 16;
    int n = n0 + nc;
    float4 v = {0.f, 0.f, 0.f, 0.f};
    if (k < K && n + 4 <= N) v = *(const float4*)(in + eoff_in + (size_t)k * N + n);
    T[nc + 0][kr + it * 16] = bf16bits(v.x);
    T[nc + 1][kr + it * 16] = bf16bits(v.y);
    T[nc + 2][kr + it * 16] = bf16bits(v.z);
    T[nc + 3][kr + it * 16] = bf16bits(v.w);
  }
  __syncthreads();
  const int nr = tid >> 2;
  const int kc = tid & 3;
#pragma unroll
  for (int it = 0; it < 2; ++it) {
    int kloc = kc * 16 + it * 8;
    int n = n0 + nr, k = k0 + kloc;
    if (n < N && k + 8 <= K)
      *(uint4*)(out + eoff_out + (size_t)n * K + k) = *(const uint4*)&T[nr][kloc];
  }
}

// ======================================================================
// GEMM1 (128Mx128N, BK=32, TRIPLE-buffer, rowpair layout, 8 waves 4Mx2N,
// per-wave 32Mx64N dual-B, 2 blocks/CU resident): h = silu(Xe*Wg).*(Xe*Wu)
// Per tile: {stage t+2 (3 gload/wave) | rd a,bg | lgkm0 | 8 G-MFMA |
//            rd bu | lgkm0 | 8 U-MFMA | vmcnt(3) | barrier}
// LDS 72KB: A[3][8KB]@0, Bg[3][8KB]@24K, Bu[3][8KB]@48K -> 2 blocks/CU.
// launch_bounds(512,4): 16 waves/CU -> VGPR capped at 128 (acc=64 AGPR).
// ======================================================================
__global__ __launch_bounds__(512, 4) void gemm_gateup4(
    const ushort* __restrict__ xb, const ushort* __restrict__ wgt,
    const ushort* __restrict__ wut, const int* __restrict__ tok_slot,
    ushort* __restrict__ h)
{
  __shared__ __align__(16) char sm[73728];
  const int tid = threadIdx.x, lane = tid & 63, wid = tid >> 6;
  const int wr = wid >> 1, wc = wid & 1;
  const int l15 = lane & 15, l4 = lane >> 4;

  // bijective XCD swizzle: 880 = 8 x 110; per expert 110 = 10 mt x 11 nt
  int wgid = (blockIdx.x & 7) * 110 + (blockIdx.x >> 3);
  const int e = wgid / 110;
  const int rem = wgid - e * 110;
  const int mt = rem % 10, nt = rem / 10;   // consecutive wgid share nt (B-panel L2 reuse)
  const int n0 = nt * 128;

  // staging sources: wave wid stages 1KB of A, Bg, Bu each (chunk = wid)
  const ushort* srcA; const ushort* srcBg; const ushort* srcBu;
  {
    int o = wid * 1024 + lane * 16;
    int row, ko; rp_src(o, row, ko);
    int tk = tok_slot[e * CAP + mt * 128 + row];
    if (tk < 0) tk = 0;                      // finite garbage; discarded
    srcA = xb + (size_t)tk * DH + ko;
    int n = n0 + row; if (n > DF - 1) n = DF - 1;
    srcBg = wgt + ((size_t)e * DF + n) * DH + ko;
    srcBu = wut + ((size_t)e * DF + n) * DH + ko;
  }
  int aoff[2], boff[4];
#pragma unroll
  for (int i = 0; i < 2; ++i) aoff[i] = rp_off(wr * 32 + i * 16 + l15, l4);
#pragma unroll
  for (int j = 0; j < 4; ++j) boff[j] = rp_off(wc * 64 + j * 16 + l15, l4);
  const int dstw = wid * 1024;

  f32x4 accG[2][4], accU[2][4];
#pragma unroll
  for (int i = 0; i < 2; ++i)
#pragma unroll
    for (int j = 0; j < 4; ++j) {
      accG[i][j] = (f32x4){0.f, 0.f, 0.f, 0.f};
      accU[i][j] = (f32x4){0.f, 0.f, 0.f, 0.f};
    }

  const int NT = DH / 32;  // 64
#pragma unroll
  for (int t0 = 0; t0 < 2; ++t0) {
    int kk = t0 * 32;
    gload16(srcA  + kk, (ushort*)(sm + t0 * 8192 + dstw));
    gload16(srcBg + kk, (ushort*)(sm + 24576 + t0 * 8192 + dstw));
    gload16(srcBu + kk, (ushort*)(sm + 49152 + t0 * 8192 + dstw));
  }
  WAITV(3);       // tile0 landed; tile1 in flight
  BARRIER();

  int rb = 0, wb = 2;
  for (int t = 0; t < NT; ++t) {
    char* Ab  = sm + rb * 8192;
    char* Bgb = sm + 24576 + rb * 8192;
    char* Bub = sm + 49152 + rb * 8192;
    if (t + 2 < NT) {
      const int kk = (t + 2) * 32;
      gload16(srcA  + kk, (ushort*)(sm + wb * 8192 + dstw));
      gload16(srcBg + kk, (ushort*)(sm + 24576 + wb * 8192 + dstw));
      gload16(srcBu + kk, (ushort*)(sm + 49152 + wb * 8192 + dstw));
    }
    bf16x8 a[2], b[4];
#pragma unroll
    for (int i = 0; i < 2; ++i) a[i] = *(const bf16x8*)(Ab + aoff[i]);
#pragma unroll
    for (int j = 0; j < 4; ++j) b[j] = *(const bf16x8*)(Bgb + boff[j]);
    LGKM0(); SCHED0();
    SETPRIO(1);
#pragma unroll
    for (int j = 0; j < 4; ++j)
#pragma unroll
      for (int i = 0; i < 2; ++i)
        accG[i][j] = __builtin_amdgcn_mfma_f32_16x16x32_bf16(a[i], b[j], accG[i][j], 0, 0, 0);
    SETPRIO(0); SCHED0();
#pragma unroll
    for (int j = 0; j < 4; ++j) b[j] = *(const bf16x8*)(Bub + boff[j]);
    LGKM0(); SCHED0();
    SETPRIO(1);
#pragma unroll
    for (int j = 0; j < 4; ++j)
#pragma unroll
      for (int i = 0; i < 2; ++i)
        accU[i][j] = __builtin_amdgcn_mfma_f32_16x16x32_bf16(a[i], b[j], accU[i][j], 0, 0, 0);
    SETPRIO(0); SCHED0();
    if (t + 2 < NT) { WAITV(3); } else { WAITV(0); }
    BARRIER();
    rb = (rb == 2) ? 0 : rb + 1;
    wb = (wb == 2) ? 0 : wb + 1;
  }
  // epilogue: SwiGLU -> h
  const size_t rowbase = (size_t)(e * CAP + mt * 128 + wr * 32);
#pragma unroll
  for (int j = 0; j < 4; ++j) {
    int col = n0 + wc * 64 + j * 16 + l15;
    if (col < DF) {
#pragma unroll
      for (int i = 0; i < 2; ++i)
#pragma unroll
        for (int r2 = 0; r2 < 4; ++r2) {
          size_t row = rowbase + i * 16 + l4 * 4 + r2;
          float gv = accG[i][j][r2], uv = accU[i][j][r2];
          h[row * DF + col] = bf16bits(gv / (1.f + __expf(-gv)) * uv);
        }
    }
  }
}

// ======================================================================
// GEMM2 (128Mx128N, BK=32, TRIPLE-buffer, rowpair layout, 8 waves 4Mx2N,
// per-wave 32Mx64N, ~3 blocks/CU): y[token] = (H*Wd)*score
// Per tile: {stage t+2 (2 gload/wave) | rd a,b | lgkm0 | 8 MFMA |
//            vmcnt(2) | barrier}
// LDS ~49KB: A[3][8KB]@0, B[3][8KB]@24K, tokc@48K, scc@48.5K
// ======================================================================
__global__ __launch_bounds__(512, 4) void gemm_down4(
    const ushort* __restrict__ h, const ushort* __restrict__ wdt,
    const int* __restrict__ tok_slot, const float* __restrict__ scores,
    float* __restrict__ y)
{
  __shared__ __align__(16) char sm[50176];
  int* tokc = (int*)(sm + 49152);
  float* scc = (float*)(sm + 49664);
  const int tid = threadIdx.x, lane = tid & 63, wid = tid >> 6;
  const int wr = wid >> 1, wc = wid & 1;
  const int l15 = lane & 15, l4 = lane >> 4;

  // bijective XCD swizzle: 1280 = 8 x 160; per expert 160 = 10 mt x 16 nt
  int wgid = (blockIdx.x & 7) * 160 + (blockIdx.x >> 3);
  const int e = wgid / 160;
  const int rem = wgid - e * 160;
  const int mt = rem % 10, nt = rem / 10;
  const int n0 = nt * 128;

  if (tid < 128) {
    int tk = tok_slot[e * CAP + mt * 128 + tid];
    tokc[tid] = tk;
    scc[tid] = (tk >= 0) ? scores[tk] : 0.f;
  }
  __syncthreads();

  const size_t hrow0 = (size_t)(e * CAP + mt * 128);
  const ushort* srcA; const ushort* srcB;
  {
    int o = wid * 1024 + lane * 16;
    int row, ko; rp_src(o, row, ko);
    srcA = h + (hrow0 + row) * DF + ko;
    srcB = wdt + ((size_t)e * DH + n0 + row) * DF + ko;
  }
  int aoff[2], boff[4];
#pragma unroll
  for (int i = 0; i < 2; ++i) aoff[i] = rp_off(wr * 32 + i * 16 + l15, l4);
#pragma unroll
  for (int j = 0; j < 4; ++j) boff[j] = rp_off(wc * 64 + j * 16 + l15, l4);
  const int dstw = wid * 1024;

  f32x4 acc[2][4];
#pragma unroll
  for (int i = 0; i < 2; ++i)
#pragma unroll
    for (int j = 0; j < 4; ++j) acc[i][j] = (f32x4){0.f, 0.f, 0.f, 0.f};

  const int NT = DF / 32;  // 43
#pragma unroll
  for (int t0 = 0; t0 < 2; ++t0) {
    int kk = t0 * 32;
    gload16(srcA + kk, (ushort*)(sm + t0 * 8192 + dstw));
    gload16(srcB + kk, (ushort*)(sm + 24576 + t0 * 8192 + dstw));
  }
  WAITV(2);
  BARRIER();

  int rb = 0, wb = 2;
  for (int t = 0; t < NT; ++t) {
    char* Ab = sm + rb * 8192;
    char* Bb = sm + 24576 + rb * 8192;
    if (t + 2 < NT) {
      const int kk = (t + 2) * 32;
      gload16(srcA + kk, (ushort*)(sm + wb * 8192 + dstw));
      gload16(srcB + kk, (ushort*)(sm + 24576 + wb * 8192 + dstw));
    }
    bf16x8 a[2], b[4];
#pragma unroll
    for (int i = 0; i < 2; ++i) a[i] = *(const bf16x8*)(Ab + aoff[i]);
#pragma unroll
    for (int j = 0; j < 4; ++j) b[j] = *(const bf16x8*)(Bb + boff[j]);
    LGKM0(); SCHED0();
    SETPRIO(1);
#pragma unroll
    for (int j = 0; j < 4; ++j)
#pragma unroll
      for (int i = 0; i < 2; ++i)
        acc[i][j] = __builtin_amdgcn_mfma_f32_16x16x32_bf16(a[i], b[j], acc[i][j], 0, 0, 0);
    SETPRIO(0); SCHED0();
    if (t + 2 < NT) { WAITV(2); } else { WAITV(0); }
    BARRIER();
    rb = (rb == 2) ? 0 : rb + 1;
    wb = (wb == 2) ? 0 : wb + 1;
  }
  // epilogue: scatter * score
  int tkr[2][4]; float sr[2][4];
#pragma unroll
  for (int i = 0; i < 2; ++i)
#pragma unroll
    for (int r = 0; r < 4; ++r) {
      int rl = wr * 32 + i * 16 + l4 * 4 + r;
      tkr[i][r] = tokc[rl];
      sr[i][r]  = scc[rl];
    }
#pragma unroll
  for (int j = 0; j < 4; ++j) {
    int col = n0 + wc * 64 + j * 16 + l15;
#pragma unroll
    for (int i = 0; i < 2; ++i)
#pragma unroll
      for (int r = 0; r < 4; ++r)
        if (tkr[i][r] >= 0)
          y[(size_t)tkr[i][r] * DH + col] = acc[i][j][r] * sr[i][r];
  }
}

extern "C" void kernel_launch(void* const* d_in, const int* in_sizes, int n_in,
                              void* d_out, int out_size, void* d_ws, size_t ws_size,
                              hipStream_t stream) {
  const float* x   = (const float*)d_in[0];
  const int*   idx = (const int*)d_in[1];
  const float* sc  = (const float*)d_in[2];
  const float* wg  = (const float*)d_in[3];
  const float* wu  = (const float*)d_in[4];
  const float* wd  = (const float*)d_in[5];
  float* y = (float*)d_out;

  const size_t OFF_KEEP = 40960;
  const size_t OFF_H    = 73728;
  const size_t SZ_H     = (size_t)NE * CAP * DF * 2;   // 28,180,480
  const size_t OFF_XB   = OFF_H + SZ_H;
  const size_t SZ_XB    = (size_t)NTOK * DH * 2;       // 33,554,432
  const size_t OFF_WGT  = OFF_XB + SZ_XB;
  const size_t SZ_W     = (size_t)NE * DH * DF * 2;    // 45,088,768
  const size_t OFF_WUT  = OFF_WGT + SZ_W;
  const size_t OFF_WDT  = OFF_WUT + SZ_W;              // total ~197 MB

  int* tok_slot = (int*)d_ws;
  int* tok_keep = (int*)((char*)d_ws + OFF_KEEP);
  ushort* hbuf = (ushort*)((char*)d_ws + OFF_H);
  ushort* xb   = (ushort*)((char*)d_ws + OFF_XB);
  ushort* wgt  = (ushort*)((char*)d_ws + OFF_WGT);
  ushort* wut  = (ushort*)((char*)d_ws + OFF_WUT);
  ushort* wdt  = (ushort*)((char*)d_ws + OFF_WDT);

  hipLaunchKernelGGL(routing_kernel, dim3(1), dim3(256), 0, stream, idx, tok_slot, tok_keep);
  hipLaunchKernelGGL(xconv_zero, dim3(NTOK), dim3(256), 0, stream, x, tok_keep, xb, y);
  hipLaunchKernelGGL(transpose_all, dim3(32, 32, 24), dim3(256), 0, stream,
                     wg, wu, wd, wgt, wut, wdt);
  hipLaunchKernelGGL(gemm_gateup4, dim3(880), dim3(512), 0, stream,
                     xb, wgt, wut, tok_slot, hbuf);
  hipLaunchKernelGGL(gemm_down4, dim3(1280), dim3(512), 0, stream,
                     hbuf, wdt, tok_slot, sc, y);
}

// Round 10
// 342.483 us; speedup vs baseline: 1.0134x; 1.0134x over previous
//
#include <hip/hip_runtime.h>
#include <hip/hip_bf16.h>
#include <cstdint>
#include <cstddef>

#define NTOK 8192
#define DH   2048
#define DF   1376
#define DFP  1408      // h row stride (K-padded for down-GEMM BK=64)
#define NE   8
#define CAP  1280

typedef __bf16 bf16x8 __attribute__((ext_vector_type(8)));
typedef float  f32x4  __attribute__((ext_vector_type(4)));

#define BARRIER() asm volatile("s_barrier" ::: "memory")
#define WAITV(n)  asm volatile("s_waitcnt vmcnt(" #n ")" ::: "memory")
#define LGKM0()   asm volatile("s_waitcnt lgkmcnt(0)" ::: "memory")
#define SCHED0()  __builtin_amdgcn_sched_barrier(0)
#define SETPRIO(n) __builtin_amdgcn_s_setprio(n)

__device__ __forceinline__ uint32_t pk2(float a, float b) {
  float2 f; f.x = a; f.y = b;
  union { __hip_bfloat162 h; uint32_t u; } cv;
  cv.h = __float22bfloat162_rn(f);
  return cv.u;
}
__device__ __forceinline__ ushort bf16bits(float a) {
  return (ushort)(pk2(a, 0.f) & 0xFFFFu);
}
__device__ __forceinline__ void gload16(const ushort* g, ushort* l) {
  __builtin_amdgcn_global_load_lds(
      (const __attribute__((address_space(1))) uint32_t*)(const void*)g,
      (__attribute__((address_space(3))) uint32_t*)(void*)l,
      16, 0, 0);
}

// ---- rowpair-128B layout within one K-half tile (rows x 32k bf16).
// Proven 0-conflict (r6-r9). element (row,k): p=row>>1, g=(row&1)*4+k/8,
// byte = p*128 + ((g ^ (p&7))<<4) + (k%8)*2
__device__ __forceinline__ void rp_src(int o, int& row, int& ko) {
  int p = o >> 7;
  int g = ((o >> 4) & 7) ^ (p & 7);
  row = p * 2 + (g >> 2);
  ko  = (g & 3) * 8;
}
__device__ __forceinline__ int rp_off(int row, int l4) {
  return ((row >> 1) << 7) + (((((row & 1) << 2) + l4) ^ ((row >> 1) & 7)) << 4);
}

// ---------------- routing ----------------
__global__ void routing_kernel(const int* __restrict__ idx, int* __restrict__ tok_slot,
                               int* __restrict__ tok_keep) {
  __shared__ int cnt[256][NE];
  const int t = threadIdx.x;
  for (int s = t; s < NE * CAP; s += 256) tok_slot[s] = -1;
  unsigned long long cA = 0ull, cB = 0ull;
  const int per = NTOK / 256, base = t * per;
  for (int i = 0; i < per; ++i) {
    int e = idx[base + i];
    unsigned long long inc = 1ull << ((e & 3) * 16);
    if (e < 4) cA += inc; else cB += inc;
  }
#pragma unroll
  for (int e = 0; e < 4; ++e) cnt[t][e]     = (int)((cA >> (e * 16)) & 0xFFFF);
#pragma unroll
  for (int e = 0; e < 4; ++e) cnt[t][4 + e] = (int)((cB >> (e * 16)) & 0xFFFF);
  __syncthreads();
  if (t < NE) {
    int run = 0;
    for (int i = 0; i < 256; ++i) { int c = cnt[i][t]; cnt[i][t] = run; run += c; }
  }
  __syncthreads();
  cA = 0ull; cB = 0ull;
#pragma unroll
  for (int e = 0; e < 4; ++e) cA |= (unsigned long long)(cnt[t][e] & 0xFFFF) << (e * 16);
#pragma unroll
  for (int e = 0; e < 4; ++e) cB |= (unsigned long long)(cnt[t][4 + e] & 0xFFFF) << (e * 16);
  for (int i = 0; i < per; ++i) {
    int token = base + i;
    int e = idx[token];
    int sh = (e & 3) * 16;
    int r = (int)(((e < 4 ? cA : cB) >> sh) & 0xFFFF);
    unsigned long long inc = 1ull << sh;
    if (e < 4) cA += inc; else cB += inc;
    bool keep = (r < CAP);
    tok_keep[token] = keep ? 1 : 0;
    if (keep) tok_slot[e * CAP + r] = token;
  }
}

// ---------------- x f32 -> bf16, fused zero of dropped y rows ----------------
__global__ void xconv_zero(const float* __restrict__ x, const int* __restrict__ keep,
                           ushort* __restrict__ xb, float* __restrict__ y) {
  const int row = blockIdx.x;
  const int c = threadIdx.x * 8;
  const size_t off = (size_t)row * DH + c;
  float4 a = *(const float4*)(x + off);
  float4 b = *(const float4*)(x + off + 4);
  uint4 p = { pk2(a.x, a.y), pk2(a.z, a.w), pk2(b.x, b.y), pk2(b.z, b.w) };
  *(uint4*)(xb + off) = p;
  if (!keep[row]) {
    float4 z = {0.f, 0.f, 0.f, 0.f};
    *(float4*)(y + off) = z;
    *(float4*)(y + off + 4) = z;
  }
}

// ---------------- w [E][K][N] f32 -> [E][N][K..ostride] bf16 ----------------
__global__ __launch_bounds__(256) void transpose_cvt(
    const float* __restrict__ in, ushort* __restrict__ out, int K, int N, int ostride) {
  __shared__ ushort T[64][72];
  const int tid = threadIdx.x;
  const int n0 = blockIdx.x * 64, k0 = blockIdx.y * 64;
  const size_t eoff_in  = (size_t)blockIdx.z * K * N;
  const size_t eoff_out = (size_t)blockIdx.z * N * ostride;
  const int kr = tid >> 4;
  const int nc = (tid & 15) * 4;
#pragma unroll
  for (int it = 0; it < 4; ++it) {
    int k = k0 + kr + it * 16;
    int n = n0 + nc;
    float4 v = {0.f, 0.f, 0.f, 0.f};
    if (k < K && n + 4 <= N) v = *(const float4*)(in + eoff_in + (size_t)k * N + n);
    T[nc + 0][kr + it * 16] = bf16bits(v.x);
    T[nc + 1][kr + it * 16] = bf16bits(v.y);
    T[nc + 2][kr + it * 16] = bf16bits(v.z);
    T[nc + 3][kr + it * 16] = bf16bits(v.w);
  }
  __syncthreads();
  const int nr = tid >> 2;
  const int kc = tid & 3;
#pragma unroll
  for (int it = 0; it < 2; ++it) {
    int kloc = kc * 16 + it * 8;
    int n = n0 + nr, k = k0 + kloc;
    if (n < N && k + 8 <= K)
      *(uint4*)(out + eoff_out + (size_t)n * ostride + k) = *(const uint4*)&T[nr][kloc];
  }
}

// ---------------- zero h pad cols [DF, DFP) ----------------
__global__ void pad_h(ushort* __restrict__ h) {
  int idx = blockIdx.x * 512 + threadIdx.x;   // 40960 total
  int row = idx >> 2, q = idx & 3;
  uint4 z = {0u, 0u, 0u, 0u};
  *(uint4*)(h + (size_t)row * DFP + DF + q * 8) = z;
}

// ======================================================================
// GEMM1 (256Mx128N, BK=64, k-half phased, 2-slot LDS, 8 waves 4Mx2N of
// 64x64 dual-B): h = silu(Xe*Wg) .* (Xe*Wu)
// LDS 128KB: A[s][kh] 4x16KB @0; Bg[s][kh] 4x8KB @64K; Bu @96K.
// Phases per K-tile u (s=u&1):
//  ph1: rd a0,bg(kh0) | stage A1(u+1),Bg1(u+1) | BAR lgkm0 16 G-MFMA | v11 BAR
//  ph2: rd bu(kh0)    | stage Bu1(u+1)         | BAR lgkm0 16 U-MFMA | v9  BAR
//  ph3: rd a1,bg(kh1) | stage A0(u+2),Bg0(u+2) | BAR lgkm0 16 G-MFMA | v11 BAR
//  ph4: rd bu(kh1)    | stage Bu0(u+2)         | BAR lgkm0 16 U-MFMA | v9  BAR
// Stage-to-first-read distance: 6 phases; vmcnt never drains (tail: 0).
// ======================================================================
__global__ __launch_bounds__(512, 2) void gemm_gateup5(
    const ushort* __restrict__ xb, const ushort* __restrict__ wgt,
    const ushort* __restrict__ wut, const int* __restrict__ tok_slot,
    ushort* __restrict__ h)
{
  __shared__ __align__(16) char sm[131072];
  const int tid = threadIdx.x, lane = tid & 63, wid = tid >> 6;
  const int wr = wid >> 1, wc = wid & 1;
  const int l15 = lane & 15, l4 = lane >> 4;

  // bijective XCD swizzle: 440 = 8 x 55; consecutive share nt (B-panel reuse)
  int wgid = (blockIdx.x & 7) * 55 + (blockIdx.x >> 3);
  const int e = wgid / 55;
  const int rem = wgid - e * 55;
  const int mt = rem % 5, nt = rem / 5;
  const int n0 = nt * 128;

  // stage sources (rowpair-inverse per-lane global addr)
  const ushort* srcA[2]; const ushort* srcBg; const ushort* srcBu;
#pragma unroll
  for (int c = 0; c < 2; ++c) {
    int o = c * 8192 + tid * 16;
    int row, ko; rp_src(o, row, ko);
    int tk = tok_slot[e * CAP + mt * 256 + row];
    if (tk < 0) tk = 0;                        // finite garbage; discarded
    srcA[c] = xb + (size_t)tk * DH + ko;
  }
  {
    int o = tid * 16;
    int row, ko; rp_src(o, row, ko);
    int n = n0 + row; if (n > DF - 1) n = DF - 1;
    srcBg = wgt + ((size_t)e * DF + n) * DH + ko;
    srcBu = wut + ((size_t)e * DF + n) * DH + ko;
  }
  int aoff[4], boff[4];
#pragma unroll
  for (int i = 0; i < 4; ++i) aoff[i] = rp_off(wr * 64 + i * 16 + l15, l4);
#pragma unroll
  for (int j = 0; j < 4; ++j) boff[j] = rp_off(wc * 64 + j * 16 + l15, l4);
  const int dstw = wid * 1024;

#define GU_A(s,kh)  (sm + (s) * 32768 + (kh) * 16384)
#define GU_BG(s,kh) (sm + 65536 + (s) * 16384 + (kh) * 8192)
#define GU_BU(s,kh) (sm + 98304 + (s) * 16384 + (kh) * 8192)
#define GU_STA(s,kh,ko_) { \
  gload16(srcA[0] + (ko_), (ushort*)(GU_A(s,kh) + dstw)); \
  gload16(srcA[1] + (ko_), (ushort*)(GU_A(s,kh) + 8192 + dstw)); }
#define GU_STBG(s,kh,ko_) gload16(srcBg + (ko_), (ushort*)(GU_BG(s,kh) + dstw))
#define GU_STBU(s,kh,ko_) gload16(srcBu + (ko_), (ushort*)(GU_BU(s,kh) + dstw))

  f32x4 accG[4][4], accU[4][4];
#pragma unroll
  for (int i = 0; i < 4; ++i)
#pragma unroll
    for (int j = 0; j < 4; ++j) {
      accG[i][j] = (f32x4){0.f, 0.f, 0.f, 0.f};
      accU[i][j] = (f32x4){0.f, 0.f, 0.f, 0.f};
    }

  const int NT = DH / 64;  // 32
  // prologue (12 loads, steady-state order)
  GU_STA(0, 0, 0);  GU_STBG(0, 0, 0);  GU_STBU(0, 0, 0);
  GU_STA(0, 1, 32); GU_STBG(0, 1, 32); GU_STBU(0, 1, 32);
  GU_STA(1, 0, 64); GU_STBG(1, 0, 64); GU_STBU(1, 0, 64);
  WAITV(9);
  BARRIER();

  bf16x8 a0[4], a1[4], bb[4];
  for (int u = 0; u < NT; ++u) {
    const int s = u & 1;
    const int k1 = (u + 1) * 64 + 32, k2 = (u + 2) * 64;
    // ---- ph1: G kh0
#pragma unroll
    for (int i = 0; i < 4; ++i) a0[i] = *(const bf16x8*)(GU_A(s, 0) + aoff[i]);
#pragma unroll
    for (int j = 0; j < 4; ++j) bb[j] = *(const bf16x8*)(GU_BG(s, 0) + boff[j]);
    if (u + 1 < NT) { GU_STA(s ^ 1, 1, k1); GU_STBG(s ^ 1, 1, k1); }
    BARRIER(); LGKM0(); SCHED0();
    SETPRIO(1);
#pragma unroll
    for (int j = 0; j < 4; ++j)
#pragma unroll
      for (int i = 0; i < 4; ++i)
        accG[i][j] = __builtin_amdgcn_mfma_f32_16x16x32_bf16(a0[i], bb[j], accG[i][j], 0, 0, 0);
    SETPRIO(0); SCHED0();
    if (u + 2 < NT) { WAITV(11); } else { WAITV(0); }
    BARRIER();
    // ---- ph2: U kh0
#pragma unroll
    for (int j = 0; j < 4; ++j) bb[j] = *(const bf16x8*)(GU_BU(s, 0) + boff[j]);
    if (u + 1 < NT) GU_STBU(s ^ 1, 1, k1);
    BARRIER(); LGKM0(); SCHED0();
    SETPRIO(1);
#pragma unroll
    for (int j = 0; j < 4; ++j)
#pragma unroll
      for (int i = 0; i < 4; ++i)
        accU[i][j] = __builtin_amdgcn_mfma_f32_16x16x32_bf16(a0[i], bb[j], accU[i][j], 0, 0, 0);
    SETPRIO(0); SCHED0();
    if (u + 2 < NT) { WAITV(9); } else { WAITV(0); }
    BARRIER();
    // ---- ph3: G kh1
#pragma unroll
    for (int i = 0; i < 4; ++i) a1[i] = *(const bf16x8*)(GU_A(s, 1) + aoff[i]);
#pragma unroll
    for (int j = 0; j < 4; ++j) bb[j] = *(const bf16x8*)(GU_BG(s, 1) + boff[j]);
    if (u + 2 < NT) { GU_STA(s, 0, k2); GU_STBG(s, 0, k2); }
    BARRIER(); LGKM0(); SCHED0();
    SETPRIO(1);
#pragma unroll
    for (int j = 0; j < 4; ++j)
#pragma unroll
      for (int i = 0; i < 4; ++i)
        accG[i][j] = __builtin_amdgcn_mfma_f32_16x16x32_bf16(a1[i], bb[j], accG[i][j], 0, 0, 0);
    SETPRIO(0); SCHED0();
    if (u + 2 < NT) { WAITV(11); } else { WAITV(0); }
    BARRIER();
    // ---- ph4: U kh1
#pragma unroll
    for (int j = 0; j < 4; ++j) bb[j] = *(const bf16x8*)(GU_BU(s, 1) + boff[j]);
    if (u + 2 < NT) GU_STBU(s, 0, k2);
    BARRIER(); LGKM0(); SCHED0();
    SETPRIO(1);
#pragma unroll
    for (int j = 0; j < 4; ++j)
#pragma unroll
      for (int i = 0; i < 4; ++i)
        accU[i][j] = __builtin_amdgcn_mfma_f32_16x16x32_bf16(a1[i], bb[j], accU[i][j], 0, 0, 0);
    SETPRIO(0); SCHED0();
    if (u + 2 < NT) { WAITV(9); } else { WAITV(0); }
    BARRIER();
  }
  // epilogue: SwiGLU -> h (stride DFP)
  const size_t rowbase = (size_t)(e * CAP + mt * 256 + wr * 64);
#pragma unroll
  for (int j = 0; j < 4; ++j) {
    int col = n0 + wc * 64 + j * 16 + l15;
    if (col < DF) {
#pragma unroll
      for (int i = 0; i < 4; ++i)
#pragma unroll
        for (int r2 = 0; r2 < 4; ++r2) {
          size_t row = rowbase + i * 16 + l4 * 4 + r2;
          float gv = accG[i][j][r2], uv = accU[i][j][r2];
          h[row * DFP + col] = bf16bits(gv / (1.f + __expf(-gv)) * uv);
        }
    }
  }
}

// ======================================================================
// GEMM2 (256Mx256N, BK=64, k-half phased, 2-slot LDS, 8 waves 2Mx4N of
// 128x64): y[token] = (H*Wd)*score.  K = DFP = 1408 -> NT=22.
// LDS 128KB: A[s][kh] 4x16KB @0; B[s][kh] 4x16KB @64K. (+tokc/scc)
// Phases per K-tile u (s=u&1):
//  ph1 (mh0,kh0): rd a(lo),b(kh0) | stage A1(u+1) | BAR lgkm0 16 MFMA | BAR
//  ph2 (mh1,kh0): rd a(hi)        | stage B1(u+1) | BAR lgkm0 16 MFMA | v8 BAR
//  ph3 (mh0,kh1): rd a(lo),b(kh1) | stage A0(u+2) | BAR lgkm0 16 MFMA | BAR
//  ph4 (mh1,kh1): rd a(hi)        | stage B0(u+2) | BAR lgkm0 16 MFMA | v8 BAR
// ======================================================================
__global__ __launch_bounds__(512, 2) void gemm_down5(
    const ushort* __restrict__ h, const ushort* __restrict__ wdt,
    const int* __restrict__ tok_slot, const float* __restrict__ scores,
    float* __restrict__ y)
{
  __shared__ __align__(16) char sm[131072];
  __shared__ int tokc[256];
  __shared__ float scc[256];
  const int tid = threadIdx.x, lane = tid & 63, wid = tid >> 6;
  const int wr = wid >> 2, wc = wid & 3;       // 2M x 4N, wave 128x64
  const int l15 = lane & 15, l4 = lane >> 4;

  // bijective XCD swizzle: 320 = 8 x 40; consecutive share nt
  int wgid = (blockIdx.x & 7) * 40 + (blockIdx.x >> 3);
  const int e = wgid / 40;
  const int rem = wgid - e * 40;
  const int mt = rem % 5, nt = rem / 5;
  const int n0 = nt * 256;

  if (tid < 256) {
    int tk = tok_slot[e * CAP + mt * 256 + tid];
    tokc[tid] = tk;
    scc[tid] = (tk >= 0) ? scores[tk] : 0.f;
  }
  __syncthreads();

  const size_t hrow0 = (size_t)(e * CAP + mt * 256);
  const ushort* srcA[2]; const ushort* srcB[2];
#pragma unroll
  for (int c = 0; c < 2; ++c) {
    int o = c * 8192 + tid * 16;
    int row, ko; rp_src(o, row, ko);
    srcA[c] = h + (hrow0 + row) * DFP + ko;
    srcB[c] = wdt + ((size_t)e * DH + n0 + row) * DFP + ko;
  }
  int aoffL[4], aoffH[4], boff[4];
#pragma unroll
  for (int i = 0; i < 4; ++i) {
    aoffL[i] = rp_off(wr * 128 + i * 16 + l15, l4);
    aoffH[i] = rp_off(wr * 128 + 64 + i * 16 + l15, l4);
  }
#pragma unroll
  for (int j = 0; j < 4; ++j) boff[j] = rp_off(wc * 64 + j * 16 + l15, l4);
  const int dstw = wid * 1024;

#define DN_A(s,kh) (sm + (s) * 32768 + (kh) * 16384)
#define DN_B(s,kh) (sm + 65536 + (s) * 32768 + (kh) * 16384)
#define DN_STA(s,kh,ko_) { \
  gload16(srcA[0] + (ko_), (ushort*)(DN_A(s,kh) + dstw)); \
  gload16(srcA[1] + (ko_), (ushort*)(DN_A(s,kh) + 8192 + dstw)); }
#define DN_STB(s,kh,ko_) { \
  gload16(srcB[0] + (ko_), (ushort*)(DN_B(s,kh) + dstw)); \
  gload16(srcB[1] + (ko_), (ushort*)(DN_B(s,kh) + 8192 + dstw)); }

  f32x4 acc[8][4];
#pragma unroll
  for (int i = 0; i < 8; ++i)
#pragma unroll
    for (int j = 0; j < 4; ++j) acc[i][j] = (f32x4){0.f, 0.f, 0.f, 0.f};

  const int NT = DFP / 64;  // 22
  // prologue (12 loads)
  DN_STA(0, 0, 0);  DN_STB(0, 0, 0);
  DN_STA(0, 1, 32); DN_STB(0, 1, 32);
  DN_STA(1, 0, 64); DN_STB(1, 0, 64);
  WAITV(8);
  BARRIER();

  bf16x8 av[4], bv[4];
  for (int u = 0; u < NT; ++u) {
    const int s = u & 1;
    const int k1 = (u + 1) * 64 + 32, k2 = (u + 2) * 64;
    // ---- ph1: mh0 kh0
#pragma unroll
    for (int i = 0; i < 4; ++i) av[i] = *(const bf16x8*)(DN_A(s, 0) + aoffL[i]);
#pragma unroll
    for (int j = 0; j < 4; ++j) bv[j] = *(const bf16x8*)(DN_B(s, 0) + boff[j]);
    if (u + 1 < NT) DN_STA(s ^ 1, 1, k1);
    BARRIER(); LGKM0(); SCHED0();
    SETPRIO(1);
#pragma unroll
    for (int j = 0; j < 4; ++j)
#pragma unroll
      for (int i = 0; i < 4; ++i)
        acc[i][j] = __builtin_amdgcn_mfma_f32_16x16x32_bf16(av[i], bv[j], acc[i][j], 0, 0, 0);
    SETPRIO(0); SCHED0();
    BARRIER();
    // ---- ph2: mh1 kh0
#pragma unroll
    for (int i = 0; i < 4; ++i) av[i] = *(const bf16x8*)(DN_A(s, 0) + aoffH[i]);
    if (u + 1 < NT) DN_STB(s ^ 1, 1, k1);
    BARRIER(); LGKM0(); SCHED0();
    SETPRIO(1);
#pragma unroll
    for (int j = 0; j < 4; ++j)
#pragma unroll
      for (int i = 0; i < 4; ++i)
        acc[4 + i][j] = __builtin_amdgcn_mfma_f32_16x16x32_bf16(av[i], bv[j], acc[4 + i][j], 0, 0, 0);
    SETPRIO(0); SCHED0();
    if (u + 2 < NT) { WAITV(8); } else { WAITV(0); }
    BARRIER();
    // ---- ph3: mh0 kh1
#pragma unroll
    for (int i = 0; i < 4; ++i) av[i] = *(const bf16x8*)(DN_A(s, 1) + aoffL[i]);
#pragma unroll
    for (int j = 0; j < 4; ++j) bv[j] = *(const bf16x8*)(DN_B(s, 1) + boff[j]);
    if (u + 2 < NT) DN_STA(s, 0, k2);
    BARRIER(); LGKM0(); SCHED0();
    SETPRIO(1);
#pragma unroll
    for (int j = 0; j < 4; ++j)
#pragma unroll
      for (int i = 0; i < 4; ++i)
        acc[i][j] = __builtin_amdgcn_mfma_f32_16x16x32_bf16(av[i], bv[j], acc[i][j], 0, 0, 0);
    SETPRIO(0); SCHED0();
    BARRIER();
    // ---- ph4: mh1 kh1
#pragma unroll
    for (int i = 0; i < 4; ++i) av[i] = *(const bf16x8*)(DN_A(s, 1) + aoffH[i]);
    if (u + 2 < NT) DN_STB(s, 0, k2);
    BARRIER(); LGKM0(); SCHED0();
    SETPRIO(1);
#pragma unroll
    for (int j = 0; j < 4; ++j)
#pragma unroll
      for (int i = 0; i < 4; ++i)
        acc[4 + i][j] = __builtin_amdgcn_mfma_f32_16x16x32_bf16(av[i], bv[j], acc[4 + i][j], 0, 0, 0);
    SETPRIO(0); SCHED0();
    if (u + 2 < NT) { WAITV(8); } else { WAITV(0); }
    BARRIER();
  }
  // epilogue: scatter * score
#pragma unroll
  for (int j = 0; j < 4; ++j) {
    int col = n0 + wc * 64 + j * 16 + l15;
#pragma unroll
    for (int i = 0; i < 8; ++i)
#pragma unroll
      for (int r = 0; r < 4; ++r) {
        int rl = wr * 128 + i * 16 + l4 * 4 + r;
        int tk = tokc[rl];
        if (tk >= 0)
          y[(size_t)tk * DH + col] = acc[i][j][r] * scc[rl];
      }
  }
}

extern "C" void kernel_launch(void* const* d_in, const int* in_sizes, int n_in,
                              void* d_out, int out_size, void* d_ws, size_t ws_size,
                              hipStream_t stream) {
  const float* x   = (const float*)d_in[0];
  const int*   idx = (const int*)d_in[1];
  const float* sc  = (const float*)d_in[2];
  const float* wg  = (const float*)d_in[3];
  const float* wu  = (const float*)d_in[4];
  const float* wd  = (const float*)d_in[5];
  float* y = (float*)d_out;

  // ws layout (~152.6 MB, proven in r4): wdt reuses wgt region after gateup
  const size_t OFF_KEEP = 40960;
  const size_t OFF_H    = 73728;
  const size_t SZ_H     = (size_t)NE * CAP * DFP * 2;  // 28,835,840
  const size_t OFF_XB   = OFF_H + SZ_H;                // 28,909,568
  const size_t SZ_XB    = (size_t)NTOK * DH * 2;       // 33,554,432
  const size_t OFF_WGT  = OFF_XB + SZ_XB;              // 62,464,000
  const size_t SZ_W     = (size_t)NE * DH * DF * 2;    // 45,088,768
  const size_t OFF_WUT  = OFF_WGT + SZ_W;              // 107,552,768

  int* tok_slot = (int*)d_ws;
  int* tok_keep = (int*)((char*)d_ws + OFF_KEEP);
  ushort* hbuf = (ushort*)((char*)d_ws + OFF_H);
  ushort* xb   = (ushort*)((char*)d_ws + OFF_XB);
  ushort* wgt  = (ushort*)((char*)d_ws + OFF_WGT);
  ushort* wut  = (ushort*)((char*)d_ws + OFF_WUT);
  ushort* wdt  = wgt;   // [E][DH][1408] bf16, 46.1 MB <= 90.2 MB region

  hipLaunchKernelGGL(routing_kernel, dim3(1), dim3(256), 0, stream, idx, tok_slot, tok_keep);
  hipLaunchKernelGGL(xconv_zero, dim3(NTOK), dim3(256), 0, stream, x, tok_keep, xb, y);
  hipLaunchKernelGGL(transpose_cvt, dim3((DF + 63) / 64, DH / 64, NE), dim3(256), 0, stream,
                     wg, wgt, DH, DF, DH);
  hipLaunchKernelGGL(transpose_cvt, dim3((DF + 63) / 64, DH / 64, NE), dim3(256), 0, stream,
                     wu, wut, DH, DF, DH);
  hipLaunchKernelGGL(pad_h, dim3(80), dim3(512), 0, stream, hbuf);
  hipLaunchKernelGGL(gemm_gateup5, dim3(440), dim3(512), 0, stream,
                     xb, wgt, wut, tok_slot, hbuf);
  hipLaunchKernelGGL(transpose_cvt, dim3(DH / 64, (DF + 63) / 64, NE), dim3(256), 0, stream,
                     wd, wdt, DF, DH, DFP);
  hipLaunchKernelGGL(gemm_down5, dim3(320), dim3(512), 0, stream,
                     hbuf, wdt, tok_slot, sc, y);
}